// Round 11
// baseline (175.744 us; speedup 1.0000x reference)
//
#include <hip/hip_runtime.h>

// SpatialAttention n=4, c=128, hw=4096 fp32 in/out.
// R11: widen wave t-tile to 32 (2 t-groups x 4 s-slots) to halve K/V LDS-read
// redundancy (4x->2x; 176->112 KB per 64-s chunk). QK: 16x16x32 f16. PV:
// 32x32x16 f16 (K=16 = one wave's s-slot). Wave-private P, fixed-max exp2
// softmax, DMA dbuf staging, 2 blocks/CU (512 thr, 77KB LDS, VGPR<=128).
// Partial O/l to ws; merge kernel divides. Prepass unchanged (proven).

#define HW 4096
#define CC 128
#define KSCALE 0.12751743f      // log2(e)/sqrt(128)
#define CEXP   8.656170245f     // 6*log2(e)
#define SMEMB  78848

typedef _Float16 half8  __attribute__((ext_vector_type(8)));
typedef _Float16 half4v __attribute__((ext_vector_type(4)));
typedef float    float4v  __attribute__((ext_vector_type(4)));
typedef float    float16v __attribute__((ext_vector_type(16)));

__device__ __forceinline__ float fast_exp2(float x) {
  return __builtin_amdgcn_exp2f(x);
}

__device__ __forceinline__ void async_copy16(void* lds, const void* g) {
  __builtin_amdgcn_global_load_lds(
      (const __attribute__((address_space(1))) unsigned int*)g,
      (__attribute__((address_space(3))) unsigned int*)lds, 16, 0, 0);
}

// LDS blob offsets: sK[2][64][128]h @0 (32KB), sV[2][128][64]h @32768 (32KB),
// sPT[8][32][24]h @65536 (12KB), sLred[2][4][32]f @77824 (1KB).
__device__ __forceinline__ _Float16* pKn(char* s, int buf, int row) {
  return (_Float16*)s + ((size_t)buf * 64 + row) * 128;
}
__device__ __forceinline__ _Float16* pVn(char* s, int buf, int row) {
  return (_Float16*)(s + 32768) + ((size_t)buf * 128 + row) * 64;
}
__device__ __forceinline__ _Float16* pPn(char* s, int w, int t) {
  return (_Float16*)(s + 65536) + ((size_t)w * 32 + t) * 24;
}
__device__ __forceinline__ float* pLn(char* s, int g, int sl) {
  return (float*)(s + 77824) + ((size_t)g * 4 + sl) * 32;
}

// ---------- prepass: K^T*KSCALE -> KT, Q^T -> QT, V -> fp16 (proven) ----------
__global__ __launch_bounds__(256)
void prepass(const float* __restrict__ K, const float* __restrict__ Q,
             const float* __restrict__ V, _Float16* __restrict__ KT,
             _Float16* __restrict__ QT, _Float16* __restrict__ Vh) {
  const int bid = blockIdx.x;
  const int tid = threadIdx.x;
  if (bid < 2048) {
    __shared__ float tile[32][65];
    const bool isK = bid < 1024;
    const int id = bid & 1023;
    const float* in = isK ? K : Q;
    _Float16* out = isK ? KT : QT;
    const float scale = isK ? KSCALE : 1.0f;
    const int c0 = (id & 3) << 5;
    const int s0 = ((id >> 2) & 63) << 6;
    const int b  = id >> 8;
    const float* ib = in + (size_t)b * CC * HW;
    _Float16* ob = out + (size_t)b * HW * CC;
    const int r  = tid >> 4;
    const int c4 = (tid & 15) * 4;
    *(float4*)&tile[r][c4]      = *(const float4*)(ib + (size_t)(c0 + r) * HW + s0 + c4);
    *(float4*)&tile[r + 16][c4] = *(const float4*)(ib + (size_t)(c0 + r + 16) * HW + s0 + c4);
    __syncthreads();
    const int s  = tid >> 2;
    const int c8 = (tid & 3) * 8;
    half8 h;
    #pragma unroll
    for (int k = 0; k < 8; ++k) h[k] = (_Float16)(tile[c8 + k][s] * scale);
    *(half8*)&ob[(size_t)(s0 + s) * CC + c0 + c8] = h;
  } else {
    const int id = bid - 2048;
    #pragma unroll
    for (int p = 0; p < 4; ++p) {
      const int f = id * 1024 + p * 256 + tid;
      const float4v v = *(const float4v*)(V + 4 * (size_t)f);
      half4v h;
      h.x = (_Float16)v.x; h.y = (_Float16)v.y; h.z = (_Float16)v.z; h.w = (_Float16)v.w;
      *(half4v*)(Vh + 4 * (size_t)f) = h;
    }
  }
}

// ---------- split-s main: 2 tg x 4 sl, mixed-shape MFMA, partial outputs ------
__global__ __launch_bounds__(512, 4)
void attn_split(const _Float16* __restrict__ KT, const _Float16* __restrict__ QT,
                const _Float16* __restrict__ Vh, float* __restrict__ Opart,
                float* __restrict__ lpart) {
  __shared__ __align__(16) char smem[SMEMB];

  const int bid  = blockIdx.x;
  const int half = bid >> 8;            // s-half
  const int b    = (bid >> 6) & 3;
  const int tt0  = (bid & 63) << 6;
  const int soff = half << 11;          // * 2048
  const int tid  = threadIdx.x;
  const int w    = tid >> 6;            // 8 waves
  const int lane = tid & 63;
  const int q    = lane >> 4;           // quad (16x16 shapes)
  const int tc   = lane & 15;
  const int g    = w >> 2;              // t-group: 32 t each
  const int sl   = w & 3;               // s-slot: 16 s of the 64-chunk
  const int t32  = lane & 31;           // 32x32 n-index
  const int eh   = lane >> 5;           // 32x32 k-half

  const _Float16* KTb = KT + (size_t)b * HW * CC;
  const _Float16* Vb  = Vh + (size_t)b * CC * HW;
  float* Op = Opart + (size_t)(half * 4 + b) * CC * HW;

  // Q B-fragments: 2 t-subtiles x 4 k-steps (32 VGPRs)
  half8 qf[2][4];
  #pragma unroll
  for (int tsub = 0; tsub < 2; ++tsub) {
    const _Float16* qp = QT + (size_t)b * HW * CC +
                         (size_t)(tt0 + 32 * g + 16 * tsub + tc) * CC + 8 * q;
    #pragma unroll
    for (int ks = 0; ks < 4; ++ks) qf[tsub][ks] = *(const half8*)(qp + 32 * ks);
  }

  auto STAGE = [&](int sn, int buf) {
    #pragma unroll
    for (int p = 0; p < 2; ++p) {
      const int kr = w * 8 + p * 4 + (lane >> 4);
      const int kg = (lane & 15) ^ (kr & 15);
      async_copy16(pKn(smem, buf, w * 8 + p * 4),
                   KTb + (size_t)(soff + sn + kr) * CC + kg * 8);
      const int vr = w * 16 + p * 8 + (lane >> 3);
      const int vg = (lane & 7) ^ (vr & 7);
      async_copy16(pVn(smem, buf, w * 16 + p * 8),
                   Vb + (size_t)vr * HW + soff + sn + vg * 8);
    }
  };

  STAGE(0, 0);

  float16v accO[4];
  #pragma unroll
  for (int es = 0; es < 4; ++es)
    #pragma unroll
    for (int i = 0; i < 16; ++i) accO[es][i] = 0.f;
  float l0 = 0.0f, l1 = 0.0f;

  __syncthreads();  // drain chunk-0 DMA

  for (int it = 0; it < 2048 / 64; ++it) {
    const int buf = it & 1;
    if (it + 1 < 2048 / 64) STAGE((it + 1) * 64, buf ^ 1);

    // ---- QK: S[own 16 s][own 32 t]; A (K-frag) shared across t-subtiles ----
    float4v acc0 = (float4v){0.f, 0.f, 0.f, 0.f};
    float4v acc1 = (float4v){0.f, 0.f, 0.f, 0.f};
    #pragma unroll
    for (int ks = 0; ks < 4; ++ks) {
      const half8 a = *(const half8*)(pKn(smem, buf, 16 * sl + tc) + ((4 * ks + q) ^ tc) * 8);
      acc0 = __builtin_amdgcn_mfma_f32_16x16x32_f16(a, qf[0][ks], acc0, 0, 0, 0);
      acc1 = __builtin_amdgcn_mfma_f32_16x16x32_f16(a, qf[1][ks], acc1, 0, 0, 0);
    }

    // ---- fixed-max softmax; write wave-private P^T[t 32][s 16] ----
    {
      const float p0 = fast_exp2(acc0.x - CEXP);
      const float p1 = fast_exp2(acc0.y - CEXP);
      const float p2 = fast_exp2(acc0.z - CEXP);
      const float p3 = fast_exp2(acc0.w - CEXP);
      l0 += (p0 + p1) + (p2 + p3);
      half4v h;
      h.x = (_Float16)p0; h.y = (_Float16)p1; h.z = (_Float16)p2; h.w = (_Float16)p3;
      *(half4v*)(pPn(smem, w, tc) + 4 * q) = h;          // s_loc = 4q+r
    }
    {
      const float p0 = fast_exp2(acc1.x - CEXP);
      const float p1 = fast_exp2(acc1.y - CEXP);
      const float p2 = fast_exp2(acc1.z - CEXP);
      const float p3 = fast_exp2(acc1.w - CEXP);
      l1 += (p0 + p1) + (p2 + p3);
      half4v h;
      h.x = (_Float16)p0; h.y = (_Float16)p1; h.z = (_Float16)p2; h.w = (_Float16)p3;
      *(half4v*)(pPn(smem, w, 16 + tc) + 4 * q) = h;
    }

    // ---- PV: O[128 e][own 32 t] over own 16 s, 32x32x16 (K=16) ----
    const half8 bp = *(const half8*)(pPn(smem, w, t32) + 8 * eh);  // B[k=s][n=t]
    #pragma unroll
    for (int es = 0; es < 4; ++es) {
      const int e = 32 * es + t32;
      const half8 av = *(const half8*)(pVn(smem, buf, e) + (((2 * sl + eh) ^ (e & 7))) * 8);
      accO[es] = __builtin_amdgcn_mfma_f32_32x32x16_f16(av, bp, accO[es], 0, 0, 0);
    }

    __syncthreads();  // drains prefetch DMA + guards dbuf
  }

  // ---- l reduction (per t-subtile, over the 4 quads) ----
  l0 += __shfl_xor(l0, 16); l0 += __shfl_xor(l0, 32);
  l1 += __shfl_xor(l1, 16); l1 += __shfl_xor(l1, 32);
  if (lane < 16) { pLn(smem, g, sl)[tc] = l0; pLn(smem, g, sl)[16 + tc] = l1; }
  __syncthreads();  // all PV done; sK/sV dead -> mbuf

  // ---- 4-way sl merge in 3 LDS rounds (plain adds; fixed-max => no rescale) --
  float* mbuf = (float*)smem;  // 2g x 32t x 132 pitch f32 = 33792 B
  float* mrow = &mbuf[((size_t)g * 32 + t32) * 132];
  for (int r = 1; r < 4; ++r) {
    if (sl == r) {
      #pragma unroll
      for (int es = 0; es < 4; ++es)
        #pragma unroll
        for (int rr = 0; rr < 4; ++rr) {
          float4v v4;
          v4.x = accO[es][4 * rr + 0]; v4.y = accO[es][4 * rr + 1];
          v4.z = accO[es][4 * rr + 2]; v4.w = accO[es][4 * rr + 3];
          *(float4v*)&mrow[32 * es + 8 * rr + 4 * eh] = v4;
        }
    }
    __syncthreads();
    if (sl == 0) {
      #pragma unroll
      for (int es = 0; es < 4; ++es)
        #pragma unroll
        for (int rr = 0; rr < 4; ++rr) {
          const float4v m = *(const float4v*)&mrow[32 * es + 8 * rr + 4 * eh];
          accO[es][4 * rr + 0] += m.x; accO[es][4 * rr + 1] += m.y;
          accO[es][4 * rr + 2] += m.z; accO[es][4 * rr + 3] += m.w;
        }
    }
    __syncthreads();
  }

  if (sl == 0) {
    const int tg = tt0 + 32 * g + t32;
    const float lsum = (pLn(smem, g, 0)[t32] + pLn(smem, g, 1)[t32]) +
                       (pLn(smem, g, 2)[t32] + pLn(smem, g, 3)[t32]);
    if (eh == 0) lpart[(size_t)(half * 4 + b) * HW + tg] = lsum;
    // C/D 32x32 layout: e = 32es + 8rr + 4*eh + i, t = t32
    #pragma unroll
    for (int es = 0; es < 4; ++es)
      #pragma unroll
      for (int rr = 0; rr < 4; ++rr) {
        const int e0 = 32 * es + 8 * rr + 4 * eh;
        Op[(size_t)(e0 + 0) * HW + tg] = accO[es][4 * rr + 0];
        Op[(size_t)(e0 + 1) * HW + tg] = accO[es][4 * rr + 1];
        Op[(size_t)(e0 + 2) * HW + tg] = accO[es][4 * rr + 2];
        Op[(size_t)(e0 + 3) * HW + tg] = accO[es][4 * rr + 3];
      }
  }
}

// ---------- merge: out = (Oa + Ob) / (la + lb) (proven) ----------
__global__ __launch_bounds__(256)
void merge_split(const float* __restrict__ Op, const float* __restrict__ lp,
                 float* __restrict__ out) {
  const int f   = blockIdx.x * 256 + threadIdx.x;
  const int row = f >> 10;                          // b*128+e, 0..511
  const int t4  = (f & 1023) << 2;
  const int b   = row >> 7;
  const float4v oa = *(const float4v*)(Op + (size_t)row * HW + t4);
  const float4v ob = *(const float4v*)(Op + ((size_t)row + 512) * HW + t4);
  const float4v la = *(const float4v*)(lp + (size_t)b * HW + t4);
  const float4v lb = *(const float4v*)(lp + ((size_t)b + 4) * HW + t4);
  float4v o;
  o.x = (oa.x + ob.x) / (la.x + lb.x);
  o.y = (oa.y + ob.y) / (la.y + lb.y);
  o.z = (oa.z + ob.z) / (la.z + lb.z);
  o.w = (oa.w + ob.w) / (la.w + lb.w);
  *(float4v*)(out + (size_t)row * HW + t4) = o;
}

extern "C" void kernel_launch(void* const* d_in, const int* in_sizes, int n_in,
                              void* d_out, int out_size, void* d_ws, size_t ws_size,
                              hipStream_t stream) {
  const float* key   = (const float*)d_in[0];
  const float* query = (const float*)d_in[1];
  const float* value = (const float*)d_in[2];
  float* out = (float*)d_out;

  const size_t TEN   = (size_t)4 * HW * CC * sizeof(_Float16);   // 4 MiB
  const size_t OPART = (size_t)2 * 4 * CC * HW * sizeof(float);  // 16 MiB
  _Float16* KT = (_Float16*)d_ws;
  _Float16* QT = (_Float16*)((char*)d_ws + TEN);
  _Float16* Vh = (_Float16*)((char*)d_ws + 2 * TEN);
  float* Opart = (float*)((char*)d_ws + 3 * TEN);
  float* lpart = (float*)((char*)d_ws + 3 * TEN + OPART);
  (void)ws_size;

  prepass<<<dim3(2560), dim3(256), 0, stream>>>(key, query, value, KT, QT, Vh);
  attn_split<<<dim3(512), dim3(512), 0, stream>>>(KT, QT, Vh, Opart, lpart);
  merge_split<<<dim3(2048), dim3(256), 0, stream>>>(Opart, lpart, out);
}